// Round 2
// baseline (9114.027 us; speedup 1.0000x reference)
//
#include <hip/hip_runtime.h>

#define BATCH 64
#define SEQ 8192
#define RDIM 80
#define RING 169          // max delay 168 + 1
#define NCHUNK (SEQ / 2)  // C=2 steps per chunk (bounded by tau_min=4 lead time)

// tanh(z) = 1 - 2/(exp(2z)+1); exact saturation, abs err ~1e-7
__device__ __forceinline__ float fast_tanh(float z) {
    float e = __expf(2.0f * z);
    return 1.0f - 2.0f / (e + 1.0f);
}

// broadcast lane q's copy of v to all lanes via v_readlane (VALU, no LDS)
__device__ __forceinline__ float rl(float v, int q) {
    return __int_as_float(__builtin_amdgcn_readlane(__float_as_int(v), q));
}

__global__ __launch_bounds__(256, 1)
void reservoir_kernel(const float* __restrict__ x,
                      const float* __restrict__ W_in,
                      const float* __restrict__ W_fb,
                      const float* __restrict__ bias,
                      float* __restrict__ out) {
    // ring[slot][i]: accumulated far-tap contributions for step s = slot (mod 169)
    __shared__ __align__(16) float ring[RING * RDIM];      // 54080 B
    // h history ping-pong: [chunk parity][step in chunk][i]
    __shared__ __align__(16) float h_hist[2][2][RDIM];     // 1280 B

    const int b    = blockIdx.x;
    const int t    = threadIdx.x;
    const int wid  = t >> 6;
    const int lane = t & 63;

    for (int i = t; i < RING * RDIM; i += 256) ring[i] = 0.0f;
    for (int i = t; i < 2 * 2 * RDIM; i += 256) ((float*)h_hist)[i] = 0.0f;

    // ---- unit assignment ----
    // wave 0: tau=1 recurrence, lanes 0..39 own row-pair p=lane.
    // waves 1..3: 160 units = 4 far taps x 40 pairs, 1 unit per lane.
    int kk, pp;
    bool unit_valid;
    if (wid == 0) {
        kk = 0;
        pp = (lane < 40) ? lane : 39;
        unit_valid = (lane < 40);
    } else {
        int g = (wid - 1) * 64 + lane;
        unit_valid = (g < 160);
        if (g > 159) g = 159;
        kk = g / 40 + 1;         // 1..4 -> tau 4,24,96,168
        pp = g % 40;
    }
    const int tau_arr[5] = {1, 4, 24, 96, 168};
    const int tau = tau_arr[kk];

    // ---- load this unit's two weight rows into registers ----
    float w0[RDIM], w1[RDIM];
    {
        const float4* r0 = (const float4*)(W_fb + (size_t)(kk * RDIM + 2 * pp) * RDIM);
        const float4* r1 = (const float4*)(W_fb + (size_t)(kk * RDIM + 2 * pp + 1) * RDIM);
        #pragma unroll
        for (int j = 0; j < RDIM / 4; ++j) {
            float4 a = r0[j], c = r1[j];
            w0[4*j+0] = a.x; w0[4*j+1] = a.y; w0[4*j+2] = a.z; w0[4*j+3] = a.w;
            w1[4*j+0] = c.x; w1[4*j+1] = c.y; w1[4*j+2] = c.z; w1[4*j+3] = c.w;
        }
    }

    // wave-0 per-lane recurrence state
    float h0 = 0.0f, h1 = 0.0f;
    float win0 = 0.f, win1 = 0.f, bi0 = 0.f, bi1 = 0.f;
    if (wid == 0 && lane < 40) {
        win0 = W_in[2 * pp];     win1 = W_in[2 * pp + 1];
        bi0  = bias[2 * pp];     bi1  = bias[2 * pp + 1];
    }
    const float* xb   = x + (size_t)b * SEQ;
    float*       outb = out + (size_t)b * SEQ * RDIM;
    float x0 = xb[0], x1 = xb[1];

    __syncthreads();

    for (int c = 0; c < NCHUNK; ++c) {
        const int s0 = 2 * c;
        if (wid == 0) {
            // ---- recurrence wave: 2 serial steps, h broadcast via readlane ----
            // prefetch next chunk's x (global latency hidden under ~1100 cyc chunk)
            float xf0 = 0.f, xf1 = 0.f;
            if (s0 + 2 < SEQ) { xf0 = xb[s0 + 2]; xf1 = xb[s0 + 3]; }
            // ring values for this chunk (final as of the last barrier)
            const int sl0 = s0 % RING;
            const int sl1 = (s0 + 1) % RING;
            float2 rg0 = ((const float2*)(ring + sl0 * RDIM))[pp];
            float2 rg1 = ((const float2*)(ring + sl1 * RDIM))[pp];

            // ---- step s0 ----
            {
                float a0 = 0.f, a1 = 0.f, c0 = 0.f, c1 = 0.f;
                #pragma unroll
                for (int q = 0; q < 40; ++q) {
                    float hq0 = rl(h0, q), hq1 = rl(h1, q);
                    a0 = fmaf(w0[2*q],   hq0, a0);
                    a1 = fmaf(w0[2*q+1], hq1, a1);
                    c0 = fmaf(w1[2*q],   hq0, c0);
                    c1 = fmaf(w1[2*q+1], hq1, c1);
                }
                float z0 = (a0 + a1) + rg0.x + bi0 + x0 * win0;
                float z1 = (c0 + c1) + rg0.y + bi1 + x0 * win1;
                h0 = 0.7f * h0 + 0.3f * fast_tanh(z0);
                h1 = 0.7f * h1 + 0.3f * fast_tanh(z1);
                if (lane < 40) {
                    ((float2*)(ring + sl0 * RDIM))[pp] = make_float2(0.f, 0.f); // retire slot
                    ((float2*)h_hist[c & 1][0])[pp] = make_float2(h0, h1);
                    ((float2*)(outb + (size_t)s0 * RDIM))[pp] = make_float2(h0, h1);
                }
            }
            // ---- step s0+1 ----
            {
                float a0 = 0.f, a1 = 0.f, c0 = 0.f, c1 = 0.f;
                #pragma unroll
                for (int q = 0; q < 40; ++q) {
                    float hq0 = rl(h0, q), hq1 = rl(h1, q);
                    a0 = fmaf(w0[2*q],   hq0, a0);
                    a1 = fmaf(w0[2*q+1], hq1, a1);
                    c0 = fmaf(w1[2*q],   hq0, c0);
                    c1 = fmaf(w1[2*q+1], hq1, c1);
                }
                float z0 = (a0 + a1) + rg1.x + bi0 + x1 * win0;
                float z1 = (c0 + c1) + rg1.y + bi1 + x1 * win1;
                h0 = 0.7f * h0 + 0.3f * fast_tanh(z0);
                h1 = 0.7f * h1 + 0.3f * fast_tanh(z1);
                if (lane < 40) {
                    ((float2*)(ring + sl1 * RDIM))[pp] = make_float2(0.f, 0.f);
                    ((float2*)h_hist[c & 1][1])[pp] = make_float2(h0, h1);
                    ((float2*)(outb + (size_t)(s0 + 1) * RDIM))[pp] = make_float2(h0, h1);
                }
            }
            x0 = xf0; x1 = xf1;
        } else if (c >= 1) {
            // ---- tap waves: consume previous chunk's h, push into future ring slots ----
            const int sp0 = 2 * (c - 1);
            const int rd  = (c - 1) & 1;
            #pragma unroll
            for (int j = 0; j < 2; ++j) {
                const int sj = sp0 + j;
                // lane q picks up h-pair q of that step, then in-wave readlane broadcast
                float2 hs = ((const float2*)h_hist[rd][j])[(lane < 40) ? lane : 39];
                float a0 = 0.f, a1 = 0.f, c0 = 0.f, c1 = 0.f;
                #pragma unroll
                for (int q = 0; q < 40; ++q) {
                    float hq0 = rl(hs.x, q), hq1 = rl(hs.y, q);
                    a0 = fmaf(w0[2*q],   hq0, a0);
                    a1 = fmaf(w0[2*q+1], hq1, a1);
                    c0 = fmaf(w1[2*q],   hq0, c0);
                    c1 = fmaf(w1[2*q+1], hq1, c1);
                }
                if (unit_valid) {
                    const int slot = (sj + tau) % RING;
                    float2* rp = (float2*)(ring + slot * RDIM) + pp;
                    float2 v = *rp;
                    v.x += (a0 + a1);
                    v.y += (c0 + c1);
                    *rp = v;
                }
            }
        }
        __syncthreads();
    }
}

extern "C" void kernel_launch(void* const* d_in, const int* in_sizes, int n_in,
                              void* d_out, int out_size, void* d_ws, size_t ws_size,
                              hipStream_t stream) {
    const float* x    = (const float*)d_in[0];   // (64, 8192, 1)
    const float* W_in = (const float*)d_in[1];   // (80, 1)
    const float* W_fb = (const float*)d_in[2];   // (5, 80, 80)
    const float* bias = (const float*)d_in[3];   // (80,)
    float* out        = (float*)d_out;           // (64, 8192, 80)

    reservoir_kernel<<<BATCH, 256, 0, stream>>>(x, W_in, W_fb, bias, out);
}

// Round 3
// 4976.153 us; speedup vs baseline: 1.8315x; 1.8315x over previous
//
#include <hip/hip_runtime.h>

#define BATCH 64
#define SEQ 8192
#define RDIM 80
#define RING 169          // max delay 168 + 1
#define NCHUNK (SEQ / 2)  // 2 steps per chunk, 1 barrier per chunk

__device__ __forceinline__ float fast_tanh(float z) {
    // tanh(z) = 1 - 2/(exp(2z)+1); exact saturation, abs err ~1e-7
    float e = __expf(2.0f * z);
    return 1.0f - 2.0f / (e + 1.0f);
}

// v + (v from lane ^ pattern) via DPP quad_perm (pure VALU, no LDS/SGPR hazard)
// 0xB1 = quad_perm(1,0,3,2) -> xor 1 ; 0x4E = quad_perm(2,3,0,1) -> xor 2
template <int CTRL>
__device__ __forceinline__ float dpp_xor_add(float v) {
    int o = __builtin_amdgcn_mov_dpp(__float_as_int(v), CTRL, 0xF, 0xF, true);
    return v + __int_as_float(o);
}

__global__ __launch_bounds__(256, 1)
void reservoir_kernel(const float* __restrict__ x,
                      const float* __restrict__ W_in,
                      const float* __restrict__ W_fb,
                      const float* __restrict__ bias,
                      float* __restrict__ out) {
    // ring[slot][i]: accumulated far-tap contributions for step s = slot (mod 169)
    __shared__ __align__(16) float ring[RING * RDIM];   // 54080 B
    __shared__ __align__(16) float h_cur[RDIM];         // wave0-private broadcast buf

    const int b    = blockIdx.x;
    const int t    = threadIdx.x;
    const int wid  = t >> 6;
    const int lane = t & 63;

    for (int i = t; i < RING * RDIM; i += 256) ring[i] = 0.0f;
    if (t < RDIM) h_cur[t] = 0.0f;

    const float* xb   = x + (size_t)b * SEQ;
    float*       outb = out + (size_t)b * (size_t)SEQ * RDIM;

    float wr[160];   // per-lane weight slice (wave0 uses first 100)

    // ---- wave-0 layout: quad q owns rows 5q..5q+4; lane (q,sub) covers j in [20*sub, 20*sub+20)
    int q = 0, sub = 0, rowA = 0, rowB = 0;
    float hA = 0.f, hB = 0.f, winA = 0.f, winB = 0.f, bA = 0.f, bB = 0.f;
    // ---- tap layout: unit g = (wid-1)*64+lane < 160 ; k=g/40 -> tau{4,24,96,168};
    //      qq=(g%40)/2 -> rows 4qq..4qq+3 ; half=g&1 -> j in [40*half, 40*half+40)
    int tap_tau = 0, qq = 0, half = 0;
    bool tap_valid = false, tap_lo = false;

    if (wid == 0) {
        q = lane >> 2; sub = lane & 3;
        rowA = 5 * q + sub;        // owned by this lane
        rowB = 5 * q + 4;          // owned by sub==0 lane
        #pragma unroll
        for (int r = 0; r < 5; ++r) {
            const float* src = W_fb + (size_t)(5 * q + r) * RDIM + 20 * sub;  // W_1 rows
            #pragma unroll
            for (int j4 = 0; j4 < 5; ++j4) {
                float4 v = ((const float4*)src)[j4];
                wr[r * 20 + 4 * j4 + 0] = v.x; wr[r * 20 + 4 * j4 + 1] = v.y;
                wr[r * 20 + 4 * j4 + 2] = v.z; wr[r * 20 + 4 * j4 + 3] = v.w;
            }
        }
        winA = W_in[rowA]; bA = bias[rowA];
        winB = W_in[rowB]; bB = bias[rowB];
    } else {
        int g = (wid - 1) * 64 + lane;
        tap_valid = (g < 160);
        int gg = tap_valid ? g : 159;
        int k = gg / 40, rem = gg % 40;
        qq = rem >> 1; half = rem & 1;
        tap_lo = (half == 0);
        const int taus[4] = {4, 24, 96, 168};
        tap_tau = taus[k];
        #pragma unroll
        for (int r = 0; r < 4; ++r) {
            const float* src = W_fb + (size_t)(k + 1) * RDIM * RDIM
                                    + (size_t)(4 * qq + r) * RDIM + 40 * half;
            #pragma unroll
            for (int j4 = 0; j4 < 10; ++j4) {
                float4 v = ((const float4*)src)[j4];
                wr[r * 40 + 4 * j4 + 0] = v.x; wr[r * 40 + 4 * j4 + 1] = v.y;
                wr[r * 40 + 4 * j4 + 2] = v.z; wr[r * 40 + 4 * j4 + 3] = v.w;
            }
        }
    }

    float x0 = xb[0], x1 = xb[1];
    __syncthreads();

    for (int c = 0; c < NCHUNK; ++c) {
        if (wid == 0) {
            // ================= recurrence wave: steps 2c, 2c+1 =================
            const int s0  = 2 * c;
            const int sl0 = s0 % RING, sl1 = (s0 + 1) % RING;
            // ring slots for this chunk are final (taps this chunk write slots >= 2c+2)
            float rgA0 = ring[sl0 * RDIM + rowA];
            float rgA1 = ring[sl1 * RDIM + rowA];
            float rgB0 = 0.f, rgB1 = 0.f;
            if (sub == 0) { rgB0 = ring[sl0 * RDIM + rowB]; rgB1 = ring[sl1 * RDIM + rowB]; }
            // retire the consumed slots for reuse 169 steps later
            ring[sl0 * RDIM + rowA] = 0.f; ring[sl1 * RDIM + rowA] = 0.f;
            if (sub == 0) { ring[sl0 * RDIM + rowB] = 0.f; ring[sl1 * RDIM + rowB] = 0.f; }
            // prefetch next chunk's x
            float xn0 = x0, xn1 = x1;
            if (s0 + 2 < SEQ) { xn0 = xb[s0 + 2]; xn1 = xb[s0 + 3]; }

            #pragma unroll
            for (int st = 0; st < 2; ++st) {
                const float xs  = st ? x1   : x0;
                const float rgA = st ? rgA1 : rgA0;
                const float rgB = st ? rgB1 : rgB0;
                // publish h_{s-1} (wave0-private; in-wave DS ordering, no barrier)
                h_cur[rowA] = hA;
                if (sub == 0) h_cur[rowB] = hB;
                // read my j-quarter (16-way broadcast groups, conflict-free)
                float hh[20];
                {
                    const float4* hp = (const float4*)(h_cur + 20 * sub);
                    #pragma unroll
                    for (int j4 = 0; j4 < 5; ++j4) {
                        float4 v = hp[j4];
                        hh[4*j4+0] = v.x; hh[4*j4+1] = v.y; hh[4*j4+2] = v.z; hh[4*j4+3] = v.w;
                    }
                }
                float dd[5] = {0.f, 0.f, 0.f, 0.f, 0.f};
                #pragma unroll
                for (int r = 0; r < 5; ++r)
                    #pragma unroll
                    for (int j = 0; j < 20; ++j)
                        dd[r] = fmaf(wr[r * 20 + j], hh[j], dd[r]);
                // quad all-reduce: every lane gets full dots for its quad's 5 rows
                #pragma unroll
                for (int r = 0; r < 5; ++r) {
                    dd[r] = dpp_xor_add<0xB1>(dd[r]);
                    dd[r] = dpp_xor_add<0x4E>(dd[r]);
                }
                float dA = (sub == 0) ? dd[0] : (sub == 1) ? dd[1] : (sub == 2) ? dd[2] : dd[3];
                float zA = dA + rgA + bA + xs * winA;
                hA = 0.7f * hA + 0.3f * fast_tanh(zA);
                outb[(size_t)(s0 + st) * RDIM + rowA] = hA;
                if (sub == 0) {
                    float zB = dd[4] + rgB + bB + xs * winB;
                    hB = 0.7f * hB + 0.3f * fast_tanh(zB);
                    outb[(size_t)(s0 + st) * RDIM + rowB] = hB;
                }
            }
            x0 = xn0; x1 = xn1;
        } else if (c > 0) {
            // ================= tap waves: consume steps 2(c-1), 2(c-1)+1 =================
            const int sp0 = 2 * (c - 1);
            // h from global out[] (written last chunk; __syncthreads fenced, L1/L2-served)
            const float* hp0 = outb + (size_t)sp0 * RDIM + 40 * half;
            const float* hp1 = hp0 + RDIM;
            float ha[40], hb[40];
            #pragma unroll
            for (int j4 = 0; j4 < 10; ++j4) {
                float4 v = ((const float4*)hp0)[j4];
                ha[4*j4+0] = v.x; ha[4*j4+1] = v.y; ha[4*j4+2] = v.z; ha[4*j4+3] = v.w;
            }
            #pragma unroll
            for (int j4 = 0; j4 < 10; ++j4) {
                float4 v = ((const float4*)hp1)[j4];
                hb[4*j4+0] = v.x; hb[4*j4+1] = v.y; hb[4*j4+2] = v.z; hb[4*j4+3] = v.w;
            }
            float dA[4] = {0.f, 0.f, 0.f, 0.f};
            float dB[4] = {0.f, 0.f, 0.f, 0.f};
            #pragma unroll
            for (int r = 0; r < 4; ++r)
                #pragma unroll
                for (int j = 0; j < 40; ++j) {
                    dA[r] = fmaf(wr[r * 40 + j], ha[j], dA[r]);
                    dB[r] = fmaf(wr[r * 40 + j], hb[j], dB[r]);
                }
            // combine j-halves across the (even,odd) lane pair
            #pragma unroll
            for (int r = 0; r < 4; ++r) {
                dA[r] = dpp_xor_add<0xB1>(dA[r]);
                dB[r] = dpp_xor_add<0xB1>(dB[r]);
            }
            if (tap_valid && tap_lo) {
                const int slA = (sp0 + tap_tau) % RING;
                const int slB = (sp0 + 1 + tap_tau) % RING;
                float4* pA = (float4*)(ring + slA * RDIM + 4 * qq);
                float4 vA = *pA;
                vA.x += dA[0]; vA.y += dA[1]; vA.z += dA[2]; vA.w += dA[3];
                *pA = vA;
                float4* pB = (float4*)(ring + slB * RDIM + 4 * qq);
                float4 vB = *pB;
                vB.x += dB[0]; vB.y += dB[1]; vB.z += dB[2]; vB.w += dB[3];
                *pB = vB;
            }
        }
        __syncthreads();
    }
}

extern "C" void kernel_launch(void* const* d_in, const int* in_sizes, int n_in,
                              void* d_out, int out_size, void* d_ws, size_t ws_size,
                              hipStream_t stream) {
    const float* x    = (const float*)d_in[0];   // (64, 8192, 1)
    const float* W_in = (const float*)d_in[1];   // (80, 1)
    const float* W_fb = (const float*)d_in[2];   // (5, 80, 80)
    const float* bias = (const float*)d_in[3];   // (80,)
    float* out        = (float*)d_out;           // (64, 8192, 80)

    reservoir_kernel<<<BATCH, 256, 0, stream>>>(x, W_in, W_fb, bias, out);
}